// Round 7
// baseline (229.475 us; speedup 1.0000x reference)
//
#include <hip/hip_runtime.h>
#include <math.h>

// Capsule dynamic routing, MI355X. Round 7: 3-dispatch chain, all-fp32 math
// (R6 lesson: bf16 u fails the 2% threshold; routing amplifies).
//   logits[b,j,n] = u[b,n,:] . V[b,j,:],  V[b,j,k] = sum_d W[k,jd]*o[b,j,d]
//   o[b,j,d]      = sum_k G[b,j,k]*W[k,jd], G[b,j,k] = sum_n c[b,j,n]*u[b,n,k]
// iter0: c uniform 0.1 -> o0 = 0.1*(colsum u)@W.
// Fusions vs R5 (6 dispatches -> 3):
//  - makeV inside each route: per-block redundant fold -> o -> V, written
//    idempotently to global Vg (keeps phase-1 V reads on the scalar path).
//  - squash inside route pass 1: last-block-per-batch (threadfence+counter)
//    folds the 8 O2 partials in fixed order (deterministic) and stores out.

#define BATCH 64
#define NN    2048
#define KD    128
#define JCAP  10
#define DCAP  16
#define JDIM  160
#define EPSQ  1e-7f
#define TPB   256

// ws layout (float offsets):
//  Sp  [64][8][128]    @ 0       (65536)
//  Gp1 [64][8][1280]   @ 65536   (655360)
//  O2p [64][8][160]    @ 720896  (81920)
//  Vg  [64][10][128]   @ 802816  (81920)
//  cnt [64] uint       @ 884736
#define WS_SP   0
#define WS_GP1  65536
#define WS_O2P  720896
#define WS_VG   802816
#define WS_CNT  884736

// ---- K1: colsum partials Sp (fp32) + zero the batch counters ----------
__global__ __launch_bounds__(TPB) void k_prep(const float* __restrict__ u,
                                              float* __restrict__ Sp,
                                              unsigned int* __restrict__ cnt) {
  const int b = blockIdx.y, tile = blockIdx.x, t = threadIdx.x;
  if (b == 0 && tile == 0 && t < BATCH) cnt[t] = 0u;
  const int k4 = (t & 31) * 4, rg = t >> 5;
  __shared__ float4 red[256];
  const float* p = u + ((size_t)(b * NN) + tile * 256 + rg * 32) * KD + k4;
  float4 a = make_float4(0.f, 0.f, 0.f, 0.f);
#pragma unroll 4
  for (int r = 0; r < 32; ++r) {
    float4 w = *(const float4*)(p + (size_t)r * KD);
    a.x += w.x; a.y += w.y; a.z += w.z; a.w += w.w;
  }
  red[t] = a;
  __syncthreads();
  if (t < 32) {
    float4 s4 = red[t];
#pragma unroll
    for (int rg2 = 1; rg2 < 8; ++rg2) {
      float4 w = red[rg2 * 32 + t];
      s4.x += w.x; s4.y += w.y; s4.z += w.z; s4.w += w.w;
    }
    *(float4*)&Sp[(size_t)(b * 8 + tile) * KD + t * 4] = s4;
  }
}

// ---- K2/K3: fold -> o -> V -> logits -> softmax -> G -> (pass1: squash) ---
__global__ __launch_bounds__(TPB) void k_route(const float* __restrict__ u,
                                               const float* __restrict__ wsro,
                                               const float* __restrict__ W,
                                               float* __restrict__ Vg,
                                               float* __restrict__ dst,
                                               float* __restrict__ out,
                                               unsigned int* __restrict__ cnt,
                                               int pass) {
  const int b = blockIdx.y, tile = blockIdx.x, t = threadIdx.x;
  const int r0 = tile * 256;
  __shared__ __align__(16) float Cs[JCAP][260];     // 10.2 KB
  __shared__ __align__(16) float Gp[4][JCAP][KD];   // 20 KB (gsum aliased)
  __shared__ float o_s[JDIM];
  __shared__ float sc[JCAP];
  __shared__ unsigned int lastflag;
  float* gsum = &Gp[0][0][0];   // 1280 floats, dead before Gp is written

  // ---- fused makeV: fold partials -> gsum -> o_s -> V (global, idempotent)
  if (pass == 0) {
    const float* SpB = wsro + WS_SP + (size_t)b * 8 * KD;
    if (t < KD) {
      float s = 0.f;
#pragma unroll
      for (int tl = 0; tl < 8; ++tl) s += SpB[tl * KD + t];
      gsum[t] = s * 0.1f;
    }
  } else {
    const float* GpB = wsro + WS_GP1 + (size_t)b * 8 * (JCAP * KD);
    for (int i = t; i < JCAP * KD; i += TPB) {
      float s = 0.f;
#pragma unroll
      for (int tl = 0; tl < 8; ++tl) s += GpB[tl * (JCAP * KD) + i];
      gsum[i] = s;
    }
  }
  __syncthreads();
  if (t < JDIM) {
    const int j = t >> 4;
    const float* gs = pass == 0 ? gsum : (gsum + j * KD);
    float acc = 0.f;
#pragma unroll 4
    for (int k = 0; k < KD; ++k) acc += gs[k] * W[k * JDIM + t];
    o_s[t] = acc;
  }
  __syncthreads();
  {
    const int k = t & 127, gg = t >> 7;
    float* vb = Vg + (size_t)b * (JCAP * KD);
#pragma unroll
    for (int i = 0; i < 5; ++i) {
      const int j = gg * 5 + i;
      const float* wp = W + k * JDIM + j * DCAP;
      float acc = 0.f;
#pragma unroll
      for (int d = 0; d < DCAP; ++d) acc += wp[d] * o_s[j * DCAP + d];
      vb[j * KD + k] = acc;   // all blocks of batch b write identical values
    }
  }
  __syncthreads();   // block's own V writes visible to its own reads

  // ---- phase 1: thread = row; V reads wave-uniform -> scalar cache ----
  {
    const float* up = u + (size_t)(b * NN + r0 + t) * KD;
    const float* vb = Vg + (size_t)b * (JCAP * KD);
    float acc[JCAP];
#pragma unroll
    for (int j = 0; j < JCAP; ++j) acc[j] = 0.f;
    for (int kc = 0; kc < KD; kc += 8) {
      float4 xa = *(const float4*)(up + kc);
      float4 xb = *(const float4*)(up + kc + 4);
#pragma unroll
      for (int j = 0; j < JCAP; ++j) {
        float4 v0 = *(const float4*)(vb + j * KD + kc);
        float4 v1 = *(const float4*)(vb + j * KD + kc + 4);
        acc[j] += xa.x * v0.x + xa.y * v0.y + xa.z * v0.z + xa.w * v0.w
                + xb.x * v1.x + xb.y * v1.y + xb.z * v1.z + xb.w * v1.w;
      }
    }
    float m = acc[0];
#pragma unroll
    for (int j = 1; j < JCAP; ++j) m = fmaxf(m, acc[j]);
    float s = 0.f;
#pragma unroll
    for (int j = 0; j < JCAP; ++j) { acc[j] = __expf(acc[j] - m); s += acc[j]; }
    const float inv = 1.f / s;
#pragma unroll
    for (int j = 0; j < JCAP; ++j) Cs[j][t] = acc[j] * inv;
  }
  __syncthreads();

  // ---- phase 2: wave = 64 rows, lane = k-pair (coalesced u reads) ----
  {
    const int wave = t >> 6, lane = t & 63;
    const int rw = wave * 64;
    float g0[JCAP], g1[JCAP];
#pragma unroll
    for (int j = 0; j < JCAP; ++j) { g0[j] = 0.f; g1[j] = 0.f; }
    const float* ub = u + (size_t)(b * NN + r0 + rw) * KD + 2 * lane;
    for (int rc = 0; rc < 64; rc += 4) {
      float ua[4], uc[4];
#pragma unroll
      for (int q = 0; q < 4; ++q) {
        float2 w = *(const float2*)(ub + (size_t)(rc + q) * KD);
        ua[q] = w.x; uc[q] = w.y;
      }
#pragma unroll
      for (int j = 0; j < JCAP; ++j) {
        float4 c4 = *(const float4*)&Cs[j][rw + rc];
        g0[j] += c4.x * ua[0] + c4.y * ua[1] + c4.z * ua[2] + c4.w * ua[3];
        g1[j] += c4.x * uc[0] + c4.y * uc[1] + c4.z * uc[2] + c4.w * uc[3];
      }
    }
    __syncthreads();   // gsum alias fully dead; safe to write Gp
#pragma unroll
    for (int j = 0; j < JCAP; ++j)
      *(float2*)&Gp[wave][j][2 * lane] = make_float2(g0[j], g1[j]);
  }
  __syncthreads();

  if (pass == 0) {
    float* g1d = dst + (size_t)(b * 8 + tile) * (JCAP * KD);
    for (int i = t; i < JCAP * KD; i += TPB)
      g1d[i] = Gp[0][0][i] + Gp[1][0][i] + Gp[2][0][i] + Gp[3][0][i];
    return;
  }

  // ---- pass 1 tail: O2 partial -> counter -> last block squashes ----
  for (int i = t; i < JCAP * KD; i += TPB)
    Gp[0][0][i] = Gp[0][0][i] + Gp[1][0][i] + Gp[2][0][i] + Gp[3][0][i];
  __syncthreads();
  if (t < JDIM) {
    const int j = t >> 4;
    float acc = 0.f;
#pragma unroll 4
    for (int k = 0; k < KD; ++k) acc += Gp[0][j][k] * W[k * JDIM + t];
    dst[(size_t)(b * 8 + tile) * JDIM + t] = acc;
  }
  __syncthreads();
  if (t == 0) {
    __threadfence();                       // publish O2 partial
    lastflag = atomicAdd(&cnt[b], 1u);     // 7 => we are the 8th block
  }
  __syncthreads();
  if (lastflag != 7u) return;
  __threadfence();                         // acquire others' partials

  const float* p = dst + (size_t)b * 8 * JDIM;
  if (t < JDIM) {
    float s = 0.f;
#pragma unroll
    for (int tl = 0; tl < 8; ++tl) s += p[tl * JDIM + t];
    o_s[t] = s;
  }
  __syncthreads();
  if (t < JCAP) {
    float s2 = 0.f;
#pragma unroll
    for (int d = 0; d < DCAP; ++d) { float x = o_s[t * DCAP + d]; s2 += x * x; }
    sc[t] = s2 / ((1.f + s2) * sqrtf(s2 + EPSQ));
  }
  __syncthreads();
  if (t < JDIM) out[b * JDIM + t] = o_s[t] * sc[t >> 4];
}

extern "C" void kernel_launch(void* const* d_in, const int* in_sizes, int n_in,
                              void* d_out, int out_size, void* d_ws, size_t ws_size,
                              hipStream_t stream) {
  const float* u = (const float*)d_in[0];   // (64,2048,128) fp32
  const float* W = (const float*)d_in[1];   // (128,160) fp32
  float* out = (float*)d_out;               // (64,10,16) fp32
  float* ws  = (float*)d_ws;

  float* Sp  = ws + WS_SP;
  float* Gp1 = ws + WS_GP1;
  float* O2p = ws + WS_O2P;
  float* Vg  = ws + WS_VG;
  unsigned int* cnt = (unsigned int*)(ws + WS_CNT);

  k_prep <<<dim3(8, BATCH), TPB, 0, stream>>>(u, Sp, cnt);
  k_route<<<dim3(8, BATCH), TPB, 0, stream>>>(u, ws, W, Vg, Gp1, out, cnt, 0);
  k_route<<<dim3(8, BATCH), TPB, 0, stream>>>(u, ws, W, Vg, O2p, out, cnt, 1);
}